// Round 14
// baseline (728.317 us; speedup 1.0000x reference)
//
#include <hip/hip_runtime.h>

namespace {

constexpr int Bn = 32, Cn = 8, Hn = 512, In = 512;
constexpr size_t HI = (size_t)Hn * In;     // 262144
constexpr float SC = 1.0f / 5000.0f;

using s16x8 = __attribute__((ext_vector_type(8))) short;
using f32x4 = __attribute__((ext_vector_type(4))) float;

__device__ __forceinline__ float actf(float x) {
    return fminf(1.0f, fmaxf(-1.0f, x));   // hardtanh
}

__device__ __forceinline__ unsigned short f2bf(float f) {   // RNE f32->bf16
    unsigned u = __builtin_bit_cast(unsigned, f);
    u += 0x7FFFu + ((u >> 16) & 1u);
    return (unsigned short)(u >> 16);
}
__device__ __forceinline__ float bf2f(unsigned short h) {
    return __builtin_bit_cast(float, (unsigned)h << 16);
}

__device__ __forceinline__ void async16(const void* g, void* l) {
    __builtin_amdgcn_global_load_lds(
        (const __attribute__((address_space(1))) unsigned*)g,
        (__attribute__((address_space(3))) unsigned*)l, 16, 0, 0);
}

#define VMCNT0 asm volatile("s_waitcnt vmcnt(0)" ::: "memory")

// ---------------------------------------------------------------------------
// bf16 MFMA GEMM: 128x128 tile, BK=32, 4 waves + XCD-colocating 1D swizzle
// (r12: FETCH 266->74 MB) + __launch_bounds__(256,3) (r10 win) +
// NEW r14: (a) conflict-free LDS layout [kc 4][row 128][16B] (banks row*4%32
// -> 2-way = free; replaces [row][64B]'s 8-way, 8.4M conflicts/dispatch);
// (b) T3-minimum 2-phase: issue stage(t+1) BEFORE compute(t), one
// vmcnt(0)+s_barrier per K-step — stage latency hides under MFMA+ds_read.
// Hazard: barrier(t) follows compute(t), so stage(t+2)->buf[t&1] cannot race.
// PCOL=false: p = A-row panel (A streamed), q = col tile, z = 0.
// PCOL=true : p = (z, col tile) (Bt streamed), q = A-row tile.   (G1)
// TRI: A lower-triangular -> kSteps = (rowTile+1)*4 (always even).
// EPI: 0: out0=bf16(act(acc))                              (G1, no bias)
//      1: v=act(acc+bias); out0=bf16(v); out1=bf16(act(zrow[r&511]*v)) (G2)
//      2: out0=bf16(act(acc+bias))                          (G3)
//      3: out0=bf16(relu(acc+bias))                         (fc1)
//      4: outf=acc+bias (fp32)                              (fc2)
// ---------------------------------------------------------------------------
template<int EPI, bool PCOL, bool TRI>
__global__ __launch_bounds__(256, 3) void mfma_gemm(
    const unsigned short* __restrict__ A,
    const unsigned short* __restrict__ Bt,
    const float* __restrict__ bias,
    const float* __restrict__ zrow,
    unsigned short* __restrict__ out0,
    unsigned short* __restrict__ out1,
    float* __restrict__ outf,
    size_t sB, size_t sC)
{
    // 2 buffers x (A 8KB | B 8KB); each matrix tile = [kc 4][row 128][16B]
    __shared__ __align__(16) char lds0[16384];
    __shared__ __align__(16) char lds1[16384];

    const int tid  = threadIdx.x;
    const int wid  = tid >> 6, lane = tid & 63;
    const int wr   = wid >> 1, wc = wid & 1;
    const int l15  = lane & 15, kq = lane >> 4;

    const int bid = blockIdx.x;
    const int p = ((bid >> 5) << 3) | (bid & 7);   // panel id (same-XCD group)
    const int q = (bid >> 3) & 3;                  // member within panel group
    const int rt = PCOL ? q : p;                   // A-row tile
    const int ct = PCOL ? (p & 3) : q;             // col tile
    const size_t zb = PCOL ? (size_t)(p >> 2) : 0;

    const char* Ab = (const char*)A + (size_t)rt * 131072;
    const char* Bb = (const char*)(Bt + zb * sB) + (size_t)ct * 131072;

    f32x4 acc[4][4] = {};

    // stage one 128x32 bf16 tile pair into [kc][row][16B]; dest = uniform
    // base + lane*16 (m104); source row stride 1024B.
    const size_t ro = (size_t)(tid & 127) * 1024;
    const int    hi16 = (tid >> 7) * 16;           // wave-uniform
    auto stage_ab = [&](char* buf, int k0b) {
        const int kb = k0b + hi16;
        async16(Ab + ro + kb,      buf + tid * 16);
        async16(Ab + ro + kb + 32, buf + 4096 + tid * 16);
        async16(Bb + ro + kb,      buf + 8192 + tid * 16);
        async16(Bb + ro + kb + 32, buf + 12288 + tid * 16);
    };

    auto compute = [&](const char* buf) {
        s16x8 a[4], b[4];
        const int ko = kq * 2048;                  // kc-slice byte offset
        #pragma unroll
        for (int m = 0; m < 4; ++m)
            a[m] = *(const s16x8*)(buf + ko + (wr * 64 + m * 16 + l15) * 16);
        #pragma unroll
        for (int n = 0; n < 4; ++n)
            b[n] = *(const s16x8*)(buf + 8192 + ko + (wc * 64 + n * 16 + l15) * 16);
        #pragma unroll
        for (int m = 0; m < 4; ++m)
            #pragma unroll
            for (int n = 0; n < 4; ++n)
                acc[m][n] = __builtin_amdgcn_mfma_f32_16x16x32_bf16(a[m], b[n], acc[m][n], 0, 0, 0);
    };

    const int kSteps = TRI ? (rt + 1) * 4 : 16;    // even

    stage_ab(lds0, 0);
    VMCNT0;
    __builtin_amdgcn_s_barrier();

    #pragma unroll 1
    for (int ks = 0; ks < kSteps; ks += 2) {
        stage_ab(lds1, (ks + 1) * 64);             // issue next BEFORE compute
        compute(lds0);
        VMCNT0;                                    // stage(t+1) complete
        __builtin_amdgcn_s_barrier();
        if (ks + 2 < kSteps) stage_ab(lds0, (ks + 2) * 64);
        compute(lds1);
        VMCNT0;
        __builtin_amdgcn_s_barrier();
    }

    // ---- epilogue: C/D layout col=lane&15, row=(lane>>4)*4+j ----
    const int cb = ct * 128 + wc * 64 + l15;
    const int rb = rt * 128 + wr * 64 + (kq << 2);
    #pragma unroll
    for (int m = 0; m < 4; ++m) {
        #pragma unroll
        for (int n = 0; n < 4; ++n) {
            const int c = cb + n * 16;
            #pragma unroll
            for (int j = 0; j < 4; ++j) {
                const int r = rb + m * 16 + j;
                float v = acc[m][n][j];
                const size_t idx = zb * sC + (size_t)r * 512 + c;
                if (EPI == 0) {
                    out0[idx] = f2bf(actf(v));
                } else if (EPI == 1) {
                    float tp = actf(v + bias[c]);
                    out0[idx] = f2bf(tp);
                    out1[idx] = f2bf(actf(zrow[r & 511] * tp));
                } else if (EPI == 2) {
                    out0[idx] = f2bf(actf(v + bias[c]));
                } else if (EPI == 3) {
                    out0[idx] = f2bf(fmaxf(v + bias[c], 0.0f));
                } else {
                    outf[idx] = v + bias[c];
                }
            }
        }
    }
}

// comb[b] = bf16( x0[b]/5000 + sum_c tp[b,c] + sum_c tz[b,c] )
__global__ __launch_bounds__(256) void reduce_both(
    const unsigned short* __restrict__ tp,
    const unsigned short* __restrict__ tz,
    const float* __restrict__ x0,
    unsigned short* __restrict__ comb)
{
    size_t idx = (size_t)blockIdx.x * 256 + threadIdx.x;   // float4 slot
    size_t b = idx >> 16;                                  // / (HI/4)
    size_t p = (idx & 65535) * 4;
    float4 xv = *(const float4*)&x0[(b * Cn) * HI + p];
    float s0 = xv.x * SC, s1 = xv.y * SC, s2 = xv.z * SC, s3 = xv.w * SC;
    #pragma unroll
    for (int c = 0; c < Cn; ++c) {
        size_t q = (b * Cn + c) * HI + p;
        ushort4 a = *(const ushort4*)&tp[q];
        ushort4 d = *(const ushort4*)&tz[q];
        s0 += bf2f(a.x) + bf2f(d.x);
        s1 += bf2f(a.y) + bf2f(d.y);
        s2 += bf2f(a.z) + bf2f(d.z);
        s3 += bf2f(a.w) + bf2f(d.w);
    }
    ushort4 o;
    o.x = f2bf(s0); o.y = f2bf(s1); o.z = f2bf(s2); o.w = f2bf(s3);
    *(ushort4*)&comb[b * HI + p] = o;
}

// xst[bc][i][k] = bf16( x[bc][k][i] * act(mask[k][i]) / 5000 )
__global__ __launch_bounds__(256) void transpose_mask(
    const float* __restrict__ x, const float* __restrict__ mask,
    unsigned short* __restrict__ xst)
{
    __shared__ float t[64][65];
    const int bc = blockIdx.z;
    const int i0 = blockIdx.x * 64, k0 = blockIdx.y * 64;
    const int r4 = threadIdx.x >> 6, cc = threadIdx.x & 63;
    const float* xp = x + (size_t)bc * HI;
    #pragma unroll
    for (int it = 0; it < 16; ++it) {
        int kl = it * 4 + r4;
        size_t g = (size_t)(k0 + kl) * In + i0 + cc;
        t[kl][cc] = xp[g] * (actf(mask[g]) * SC);
    }
    __syncthreads();
    unsigned short* op = xst + (size_t)bc * HI;
    #pragma unroll
    for (int it = 0; it < 16; ++it) {
        int il = it * 4 + r4;
        op[(size_t)(i0 + il) * Hn + k0 + cc] = f2bf(t[cc][il]);
    }
}

__global__ __launch_bounds__(256) void prep_wpe_bf(
    const float* __restrict__ Wp, const float* __restrict__ Wpd,
    unsigned short* __restrict__ o)
{
    int idx = blockIdx.x * 256 + threadIdx.x;
    int i = idx >> 9, j = idx & 511;
    o[idx] = f2bf(Wp[idx] + (i == j ? Wpd[i] : 0.0f));
}

__global__ __launch_bounds__(256) void conv_bf(
    const float* __restrict__ s, unsigned short* __restrict__ o)
{
    int idx = blockIdx.x * 256 + threadIdx.x;
    o[idx] = f2bf(s[idx]);
}

__global__ __launch_bounds__(64) void rowsum(
    const float* __restrict__ W, float* __restrict__ zr)
{
    int h = blockIdx.x, l = threadIdx.x;
    float s = 0.0f;
    for (int k = l; k < Hn; k += 64) s += W[h * Hn + k];
    #pragma unroll
    for (int off = 32; off; off >>= 1) s += __shfl_down(s, off, 64);
    if (!l) zr[h] = s;
}

} // namespace

extern "C" void kernel_launch(void* const* d_in, const int* in_sizes, int n_in,
                              void* d_out, int out_size, void* d_ws, size_t ws_size,
                              hipStream_t stream)
{
    const float* input  = (const float*)d_in[0];
    const float* p_mask = (const float*)d_in[1];
    const float* Wp     = (const float*)d_in[2];
    const float* Wpd    = (const float*)d_in[3];
    const float* Wzp    = (const float*)d_in[4];
    const float* plw    = (const float*)d_in[5];
    const float* plb    = (const float*)d_in[6];
    const float* zlw    = (const float*)d_in[7];
    const float* zlb    = (const float*)d_in[8];
    const float* f1w    = (const float*)d_in[9];
    const float* f1b    = (const float*)d_in[10];
    const float* f2w    = (const float*)d_in[11];
    const float* f2b    = (const float*)d_in[12];

    constexpr size_t WB = 512 * 512 * 2;   // one bf16 weight matrix
    char* w = (char*)d_ws;
    auto alloc = [&](size_t bytes) { char* p = w; w += (bytes + 255) & ~255ull; return p; };

    unsigned short* Wpeb  = (unsigned short*)alloc(WB);
    unsigned short* plwb  = (unsigned short*)alloc(WB);
    unsigned short* zlwb  = (unsigned short*)alloc(WB);
    unsigned short* f1wb  = (unsigned short*)alloc(WB);
    unsigned short* f2wb  = (unsigned short*)alloc(WB);
    float*          zrw   = (float*)alloc(512 * 4);
    unsigned short* combb = (unsigned short*)alloc((size_t)Bn * HI * 2);   // 16.8 MB
    unsigned short* out1  = (unsigned short*)alloc((size_t)Bn * HI * 2);   // 16.8 MB

    size_t fixedB = (size_t)(w - (char*)d_ws);
    int chunk = 32;
    while (chunk > 1 &&
           fixedB + 4ull * (size_t)chunk * Cn * HI * 2 + 4096 > ws_size)
        chunk >>= 1;
    const size_t CB = (size_t)chunk * Cn * HI * 2;
    unsigned short* xst   = (unsigned short*)alloc(CB);   // reused for tz
    unsigned short* tpact = (unsigned short*)alloc(CB);
    unsigned short* tpb   = (unsigned short*)alloc(CB);
    unsigned short* tzin  = (unsigned short*)alloc(CB);
    unsigned short* tzb   = xst;

    prep_wpe_bf<<<512 * 512 / 256, 256, 0, stream>>>(Wp, Wpd, Wpeb);
    conv_bf<<<1024, 256, 0, stream>>>(plw, plwb);
    conv_bf<<<1024, 256, 0, stream>>>(zlw, zlwb);
    conv_bf<<<1024, 256, 0, stream>>>(f1w, f1wb);
    conv_bf<<<1024, 256, 0, stream>>>(f2w, f2wb);
    rowsum<<<512, 64, 0, stream>>>(Wzp, zrw);

    for (int b0 = 0; b0 < Bn; b0 += chunk) {
        const int nc = chunk * Cn;
        const float* inp_c = input + (size_t)b0 * Cn * HI;

        // xst = bf16(x^T * act(mask)/5000)
        transpose_mask<<<dim3(8, 8, nc), 256, 0, stream>>>(inp_c, p_mask, xst);
        // G1: tpact[bc] = act(Wpe @ xst[bc]^T)  — PCOL (xst streamed) + TRI
        mfma_gemm<0, true, true><<<nc * 16, 256, 0, stream>>>(
            Wpeb, xst, nullptr, nullptr, tpact, nullptr, nullptr, HI, HI);
        // G2: tp = act(tpact @ plw^T + plb); tzin = act(zrow*tp)
        mfma_gemm<1, false, false><<<nc * 16, 256, 0, stream>>>(
            tpact, plwb, plb, zrw, tpb, tzin, nullptr, 0, 0);
        // G3: tz = act(tzin @ zlw^T + zlb)
        mfma_gemm<2, false, false><<<nc * 16, 256, 0, stream>>>(
            tzin, zlwb, zlb, nullptr, tzb, nullptr, nullptr, 0, 0);
        // comb = x0/5000 + sum_c tp + sum_c tz
        reduce_both<<<chunk * 256, 256, 0, stream>>>(
            tpb, tzb, inp_c, combb + (size_t)b0 * HI);
    }

    // fc1: out1 = relu(combb @ f1w^T + f1b)
    mfma_gemm<3, false, false><<<512, 256, 0, stream>>>(
        combb, f1wb, f1b, nullptr, out1, nullptr, nullptr, 0, 0);
    // fc2: out = out1 @ f2w^T + f2b   (fp32)
    mfma_gemm<4, false, false><<<512, 256, 0, stream>>>(
        out1, f2wb, f2b, nullptr, nullptr, nullptr, (float*)d_out, 0, 0);
}

// Round 15
// 560.071 us; speedup vs baseline: 1.3004x; 1.3004x over previous
//
#include <hip/hip_runtime.h>

namespace {

constexpr int Bn = 32, Cn = 8, Hn = 512, In = 512;
constexpr size_t HI = (size_t)Hn * In;     // 262144
constexpr float SC = 1.0f / 5000.0f;

using s16x8 = __attribute__((ext_vector_type(8))) short;
using f32x4 = __attribute__((ext_vector_type(4))) float;

__device__ __forceinline__ float actf(float x) {
    return fminf(1.0f, fmaxf(-1.0f, x));   // hardtanh
}

__device__ __forceinline__ unsigned short f2bf(float f) {   // RNE f32->bf16
    unsigned u = __builtin_bit_cast(unsigned, f);
    u += 0x7FFFu + ((u >> 16) & 1u);
    return (unsigned short)(u >> 16);
}
__device__ __forceinline__ float bf2f(unsigned short h) {
    return __builtin_bit_cast(float, (unsigned)h << 16);
}

__device__ __forceinline__ void async16(const void* g, void* l) {
    __builtin_amdgcn_global_load_lds(
        (const __attribute__((address_space(1))) unsigned*)g,
        (__attribute__((address_space(3))) unsigned*)l, 16, 0, 0);
}

// ---------------------------------------------------------------------------
// bf16 MFMA GEMM: 128x128 tile, BK=32, 4 waves (round-3 body) +
// XCD-colocating 1D swizzle (r12: FETCH 266->74 MB) + __launch_bounds__(256,3)
// (r10 win) + NEW r15: XOR bank-swizzle done the m173 way — source column
// permuted WITHIN its 64B group (coalescing unchanged, unlike r14's failed
// relayout), LDS dest stays linear, read applies the same XOR.
//   store: thread (r0s,c0s) fetches col c0s ^ (((r0s>>1)&3)<<4)
//   read : kx = kq*16 ^ (((l15>>1)&3)<<4)   (per-lane constant)
// Bank groups become (l15&1)<<2 | (kq^((l15>>1)&3)): 8 groups x 2 lanes
// = 2-way = free (m136), vs champion's 8-way (8.4M conflicts/dispatch).
// PCOL=false: p = A-row panel (A streamed), q = col tile, z = 0.
// PCOL=true : p = (z, col tile) (Bt streamed), q = A-row tile.   (G1)
// TRI: A lower-triangular -> kSteps = (rowTile+1)*4.
// EPI: 0: out0=bf16(act(acc))                              (G1, no bias)
//      1: v=act(acc+bias); out0=bf16(v); out1=bf16(act(zrow[r&511]*v)) (G2)
//      2: out0=bf16(act(acc+bias))                          (G3)
//      3: out0=bf16(relu(acc+bias))                         (fc1)
//      4: outf=acc+bias (fp32)                              (fc2)
// ---------------------------------------------------------------------------
template<int EPI, bool PCOL, bool TRI>
__global__ __launch_bounds__(256, 3) void mfma_gemm(
    const unsigned short* __restrict__ A,
    const unsigned short* __restrict__ Bt,
    const float* __restrict__ bias,
    const float* __restrict__ zrow,
    unsigned short* __restrict__ out0,
    unsigned short* __restrict__ out1,
    float* __restrict__ outf,
    size_t sB, size_t sC)
{
    __shared__ __align__(16) unsigned short As[128 * 32];
    __shared__ __align__(16) unsigned short Bs[128 * 32];

    const int tid  = threadIdx.x;
    const int wid  = tid >> 6, lane = tid & 63;
    const int wr   = wid >> 1, wc = wid & 1;
    const int l15  = lane & 15, kq = lane >> 4;

    const int bid = blockIdx.x;
    const int p = ((bid >> 5) << 3) | (bid & 7);   // panel id (same-XCD group)
    const int q = (bid >> 3) & 3;                  // member within panel group
    const int rt = PCOL ? q : p;                   // A-row tile
    const int ct = PCOL ? (p & 3) : q;             // col tile
    const size_t zb = PCOL ? (size_t)(p >> 2) : 0;

    const char* Ab = (const char*)A + (size_t)rt * 131072;
    const char* Bb = (const char*)(Bt + zb * sB) + (size_t)ct * 131072;

    f32x4 acc[4][4] = {};

    const int o0  = tid * 16;
    const int r0s = o0 >> 6;                       // tid/4: tile row
    const int c0s = o0 & 63;                       // byte within 64B row chunk
    // XOR-swizzled source column: permutes within the 4-thread group's 64B
    // region (coalescing unchanged). (64+r0s)>>1 & 3 == (32+(r0s>>1)) & 3
    // == (r0s>>1)&3, so one value serves both staging rows.
    const int csw = c0s ^ (((r0s >> 1) & 3) << 4);

    const int kSteps = TRI ? (rt + 1) * 4 : 16;

    for (int ks = 0; ks < kSteps; ++ks) {
        const int k0b = ks * 64;
        async16(Ab + (size_t)r0s * 1024 + k0b + csw,        (char*)As + wid * 1024);
        async16(Ab + (size_t)(64 + r0s) * 1024 + k0b + csw, (char*)As + 4096 + wid * 1024);
        async16(Bb + (size_t)r0s * 1024 + k0b + csw,        (char*)Bs + wid * 1024);
        async16(Bb + (size_t)(64 + r0s) * 1024 + k0b + csw, (char*)Bs + 4096 + wid * 1024);
        __syncthreads();

        s16x8 a[4], b[4];
        // read-side XOR: row = *+l15, (row>>1)&3 == (l15>>1)&3 (m*16, wr*64
        // are multiples of 8) -> per-lane constant.
        const int kx = kq * 16 ^ (((l15 >> 1) & 3) << 4);
        const int ar = wr * 64 + l15;
        const int br = wc * 64 + l15;
        #pragma unroll
        for (int m = 0; m < 4; ++m)
            a[m] = *(const s16x8*)((const char*)As + (size_t)(ar + m * 16) * 64 + kx);
        #pragma unroll
        for (int n = 0; n < 4; ++n)
            b[n] = *(const s16x8*)((const char*)Bs + (size_t)(br + n * 16) * 64 + kx);
        #pragma unroll
        for (int m = 0; m < 4; ++m)
            #pragma unroll
            for (int n = 0; n < 4; ++n)
                acc[m][n] = __builtin_amdgcn_mfma_f32_16x16x32_bf16(a[m], b[n], acc[m][n], 0, 0, 0);
        __syncthreads();
    }

    // ---- epilogue: C/D layout col=lane&15, row=(lane>>4)*4+j ----
    const int cb = ct * 128 + wc * 64 + l15;
    const int rb = rt * 128 + wr * 64 + (kq << 2);
    #pragma unroll
    for (int m = 0; m < 4; ++m) {
        #pragma unroll
        for (int n = 0; n < 4; ++n) {
            const int c = cb + n * 16;
            #pragma unroll
            for (int j = 0; j < 4; ++j) {
                const int r = rb + m * 16 + j;
                float v = acc[m][n][j];
                const size_t idx = zb * sC + (size_t)r * 512 + c;
                if (EPI == 0) {
                    out0[idx] = f2bf(actf(v));
                } else if (EPI == 1) {
                    float tp = actf(v + bias[c]);
                    out0[idx] = f2bf(tp);
                    out1[idx] = f2bf(actf(zrow[r & 511] * tp));
                } else if (EPI == 2) {
                    out0[idx] = f2bf(actf(v + bias[c]));
                } else if (EPI == 3) {
                    out0[idx] = f2bf(fmaxf(v + bias[c], 0.0f));
                } else {
                    outf[idx] = v + bias[c];
                }
            }
        }
    }
}

// comb[b] = bf16( x0[b]/5000 + sum_c tp[b,c] + sum_c tz[b,c] )
__global__ __launch_bounds__(256) void reduce_both(
    const unsigned short* __restrict__ tp,
    const unsigned short* __restrict__ tz,
    const float* __restrict__ x0,
    unsigned short* __restrict__ comb)
{
    size_t idx = (size_t)blockIdx.x * 256 + threadIdx.x;   // float4 slot
    size_t b = idx >> 16;                                  // / (HI/4)
    size_t p = (idx & 65535) * 4;
    float4 xv = *(const float4*)&x0[(b * Cn) * HI + p];
    float s0 = xv.x * SC, s1 = xv.y * SC, s2 = xv.z * SC, s3 = xv.w * SC;
    #pragma unroll
    for (int c = 0; c < Cn; ++c) {
        size_t q = (b * Cn + c) * HI + p;
        ushort4 a = *(const ushort4*)&tp[q];
        ushort4 d = *(const ushort4*)&tz[q];
        s0 += bf2f(a.x) + bf2f(d.x);
        s1 += bf2f(a.y) + bf2f(d.y);
        s2 += bf2f(a.z) + bf2f(d.z);
        s3 += bf2f(a.w) + bf2f(d.w);
    }
    ushort4 o;
    o.x = f2bf(s0); o.y = f2bf(s1); o.z = f2bf(s2); o.w = f2bf(s3);
    *(ushort4*)&comb[b * HI + p] = o;
}

// xst[bc][i][k] = bf16( x[bc][k][i] * act(mask[k][i]) / 5000 )
__global__ __launch_bounds__(256) void transpose_mask(
    const float* __restrict__ x, const float* __restrict__ mask,
    unsigned short* __restrict__ xst)
{
    __shared__ float t[64][65];
    const int bc = blockIdx.z;
    const int i0 = blockIdx.x * 64, k0 = blockIdx.y * 64;
    const int r4 = threadIdx.x >> 6, cc = threadIdx.x & 63;
    const float* xp = x + (size_t)bc * HI;
    #pragma unroll
    for (int it = 0; it < 16; ++it) {
        int kl = it * 4 + r4;
        size_t g = (size_t)(k0 + kl) * In + i0 + cc;
        t[kl][cc] = xp[g] * (actf(mask[g]) * SC);
    }
    __syncthreads();
    unsigned short* op = xst + (size_t)bc * HI;
    #pragma unroll
    for (int it = 0; it < 16; ++it) {
        int il = it * 4 + r4;
        op[(size_t)(i0 + il) * Hn + k0 + cc] = f2bf(t[cc][il]);
    }
}

__global__ __launch_bounds__(256) void prep_wpe_bf(
    const float* __restrict__ Wp, const float* __restrict__ Wpd,
    unsigned short* __restrict__ o)
{
    int idx = blockIdx.x * 256 + threadIdx.x;
    int i = idx >> 9, j = idx & 511;
    o[idx] = f2bf(Wp[idx] + (i == j ? Wpd[i] : 0.0f));
}

__global__ __launch_bounds__(256) void conv_bf(
    const float* __restrict__ s, unsigned short* __restrict__ o)
{
    int idx = blockIdx.x * 256 + threadIdx.x;
    o[idx] = f2bf(s[idx]);
}

__global__ __launch_bounds__(64) void rowsum(
    const float* __restrict__ W, float* __restrict__ zr)
{
    int h = blockIdx.x, l = threadIdx.x;
    float s = 0.0f;
    for (int k = l; k < Hn; k += 64) s += W[h * Hn + k];
    #pragma unroll
    for (int off = 32; off; off >>= 1) s += __shfl_down(s, off, 64);
    if (!l) zr[h] = s;
}

} // namespace

extern "C" void kernel_launch(void* const* d_in, const int* in_sizes, int n_in,
                              void* d_out, int out_size, void* d_ws, size_t ws_size,
                              hipStream_t stream)
{
    const float* input  = (const float*)d_in[0];
    const float* p_mask = (const float*)d_in[1];
    const float* Wp     = (const float*)d_in[2];
    const float* Wpd    = (const float*)d_in[3];
    const float* Wzp    = (const float*)d_in[4];
    const float* plw    = (const float*)d_in[5];
    const float* plb    = (const float*)d_in[6];
    const float* zlw    = (const float*)d_in[7];
    const float* zlb    = (const float*)d_in[8];
    const float* f1w    = (const float*)d_in[9];
    const float* f1b    = (const float*)d_in[10];
    const float* f2w    = (const float*)d_in[11];
    const float* f2b    = (const float*)d_in[12];

    constexpr size_t WB = 512 * 512 * 2;   // one bf16 weight matrix
    char* w = (char*)d_ws;
    auto alloc = [&](size_t bytes) { char* p = w; w += (bytes + 255) & ~255ull; return p; };

    unsigned short* Wpeb  = (unsigned short*)alloc(WB);
    unsigned short* plwb  = (unsigned short*)alloc(WB);
    unsigned short* zlwb  = (unsigned short*)alloc(WB);
    unsigned short* f1wb  = (unsigned short*)alloc(WB);
    unsigned short* f2wb  = (unsigned short*)alloc(WB);
    float*          zrw   = (float*)alloc(512 * 4);
    unsigned short* combb = (unsigned short*)alloc((size_t)Bn * HI * 2);   // 16.8 MB
    unsigned short* out1  = (unsigned short*)alloc((size_t)Bn * HI * 2);   // 16.8 MB

    size_t fixedB = (size_t)(w - (char*)d_ws);
    int chunk = 32;
    while (chunk > 1 &&
           fixedB + 4ull * (size_t)chunk * Cn * HI * 2 + 4096 > ws_size)
        chunk >>= 1;
    const size_t CB = (size_t)chunk * Cn * HI * 2;
    unsigned short* xst   = (unsigned short*)alloc(CB);   // reused for tz
    unsigned short* tpact = (unsigned short*)alloc(CB);
    unsigned short* tpb   = (unsigned short*)alloc(CB);
    unsigned short* tzin  = (unsigned short*)alloc(CB);
    unsigned short* tzb   = xst;

    prep_wpe_bf<<<512 * 512 / 256, 256, 0, stream>>>(Wp, Wpd, Wpeb);
    conv_bf<<<1024, 256, 0, stream>>>(plw, plwb);
    conv_bf<<<1024, 256, 0, stream>>>(zlw, zlwb);
    conv_bf<<<1024, 256, 0, stream>>>(f1w, f1wb);
    conv_bf<<<1024, 256, 0, stream>>>(f2w, f2wb);
    rowsum<<<512, 64, 0, stream>>>(Wzp, zrw);

    for (int b0 = 0; b0 < Bn; b0 += chunk) {
        const int nc = chunk * Cn;
        const float* inp_c = input + (size_t)b0 * Cn * HI;

        // xst = bf16(x^T * act(mask)/5000)
        transpose_mask<<<dim3(8, 8, nc), 256, 0, stream>>>(inp_c, p_mask, xst);
        // G1: tpact[bc] = act(Wpe @ xst[bc]^T)  — PCOL (xst streamed) + TRI
        mfma_gemm<0, true, true><<<nc * 16, 256, 0, stream>>>(
            Wpeb, xst, nullptr, nullptr, tpact, nullptr, nullptr, HI, HI);
        // G2: tp = act(tpact @ plw^T + plb); tzin = act(zrow*tp)
        mfma_gemm<1, false, false><<<nc * 16, 256, 0, stream>>>(
            tpact, plwb, plb, zrw, tpb, tzin, nullptr, 0, 0);
        // G3: tz = act(tzin @ zlw^T + zlb)
        mfma_gemm<2, false, false><<<nc * 16, 256, 0, stream>>>(
            tzin, zlwb, zlb, nullptr, tzb, nullptr, nullptr, 0, 0);
        // comb = x0/5000 + sum_c tp + sum_c tz
        reduce_both<<<chunk * 256, 256, 0, stream>>>(
            tpb, tzb, inp_c, combb + (size_t)b0 * HI);
    }

    // fc1: out1 = relu(combb @ f1w^T + f1b)
    mfma_gemm<3, false, false><<<512, 256, 0, stream>>>(
        combb, f1wb, f1b, nullptr, out1, nullptr, nullptr, 0, 0);
    // fc2: out = out1 @ f2w^T + f2b   (fp32)
    mfma_gemm<4, false, false><<<512, 256, 0, stream>>>(
        out1, f2wb, f2b, nullptr, nullptr, nullptr, (float*)d_out, 0, 0);
}

// Round 16
// 555.894 us; speedup vs baseline: 1.3102x; 1.0075x over previous
//
#include <hip/hip_runtime.h>

namespace {

constexpr int Bn = 32, Cn = 8, Hn = 512, In = 512;
constexpr size_t HI = (size_t)Hn * In;     // 262144
constexpr float SC = 1.0f / 5000.0f;

using s16x8 = __attribute__((ext_vector_type(8))) short;
using f32x4 = __attribute__((ext_vector_type(4))) float;

__device__ __forceinline__ float actf(float x) {
    return fminf(1.0f, fmaxf(-1.0f, x));   // hardtanh
}

__device__ __forceinline__ unsigned short f2bf(float f) {   // RNE f32->bf16
    unsigned u = __builtin_bit_cast(unsigned, f);
    u += 0x7FFFu + ((u >> 16) & 1u);
    return (unsigned short)(u >> 16);
}
__device__ __forceinline__ float bf2f(unsigned short h) {
    return __builtin_bit_cast(float, (unsigned)h << 16);
}

__device__ __forceinline__ void async16(const void* g, void* l) {
    __builtin_amdgcn_global_load_lds(
        (const __attribute__((address_space(1))) unsigned*)g,
        (__attribute__((address_space(3))) unsigned*)l, 16, 0, 0);
}

#define CFENCE asm volatile("" ::: "memory")

// ---------------------------------------------------------------------------
// bf16 MFMA GEMM: 128x128 tile, BK=32, 4 waves + XCD swizzle (r12) +
// (256,3) occupancy (r10) + free XOR bank-swizzle (r15, conflicts=0) +
// NEW r16: pure T4 counted-vmcnt double-buffer. Per K-step:
//   vmcnt(4)   — wait tile t only; tile t+1's 4 loads STAY IN FLIGHT
//   s_barrier  — LDS visible to all waves
//   compute(t) — 8 ds_read + 16 MFMA (ds_reads complete before post-barrier:
//                compiler inserts lgkmcnt before consuming MFMAs)
//   s_barrier  — all waves done reading buf[t&1]
//   stage(t+2) -> buf[t&1]  (issue-to-wait distance = one compute phase)
// Unroll-by-2 => buffers statically indexed (no rotation/spill, rule #20).
// Final pair uses vmcnt(0). r14's failure was drain0-after-issue + layout;
// this isolates the counted wait (m218: counted-vs-drain0 is the lever).
// PCOL/TRI/EPI semantics as before.
// ---------------------------------------------------------------------------
template<int EPI, bool PCOL, bool TRI>
__global__ __launch_bounds__(256, 3) void mfma_gemm(
    const unsigned short* __restrict__ A,
    const unsigned short* __restrict__ Bt,
    const float* __restrict__ bias,
    const float* __restrict__ zrow,
    unsigned short* __restrict__ out0,
    unsigned short* __restrict__ out1,
    float* __restrict__ outf,
    size_t sB, size_t sC)
{
    __shared__ __align__(16) char lds[2][16384];   // [buf][A 8KB | B 8KB]

    const int tid  = threadIdx.x;
    const int wid  = tid >> 6, lane = tid & 63;
    const int wr   = wid >> 1, wc = wid & 1;
    const int l15  = lane & 15, kq = lane >> 4;

    const int bid = blockIdx.x;
    const int p = ((bid >> 5) << 3) | (bid & 7);   // panel id (same-XCD group)
    const int q = (bid >> 3) & 3;                  // member within panel group
    const int rt = PCOL ? q : p;                   // A-row tile
    const int ct = PCOL ? (p & 3) : q;             // col tile
    const size_t zb = PCOL ? (size_t)(p >> 2) : 0;

    const char* Ab = (const char*)A + (size_t)rt * 131072;
    const char* Bb = (const char*)(Bt + zb * sB) + (size_t)ct * 131072;

    f32x4 acc[4][4] = {};

    const int o0  = tid * 16;
    const int r0s = o0 >> 6;                       // tid/4: tile row
    const int c0s = o0 & 63;                       // byte within 64B row chunk
    const int csw = c0s ^ (((r0s >> 1) & 3) << 4); // r15 XOR (coalescing-safe)

    auto stage = [&](char* buf, int k0b) {
        async16(Ab + (size_t)r0s * 1024 + k0b + csw,        buf + wid * 1024);
        async16(Ab + (size_t)(64 + r0s) * 1024 + k0b + csw, buf + 4096 + wid * 1024);
        async16(Bb + (size_t)r0s * 1024 + k0b + csw,        buf + 8192 + wid * 1024);
        async16(Bb + (size_t)(64 + r0s) * 1024 + k0b + csw, buf + 12288 + wid * 1024);
    };
    auto compute = [&](const char* buf) {
        s16x8 a[4], b[4];
        const int kx = kq * 16 ^ (((l15 >> 1) & 3) << 4);
        const int ar = wr * 64 + l15;
        const int br = wc * 64 + l15;
        #pragma unroll
        for (int m = 0; m < 4; ++m)
            a[m] = *(const s16x8*)(buf + (size_t)(ar + m * 16) * 64 + kx);
        #pragma unroll
        for (int n = 0; n < 4; ++n)
            b[n] = *(const s16x8*)(buf + 8192 + (size_t)(br + n * 16) * 64 + kx);
        #pragma unroll
        for (int m = 0; m < 4; ++m)
            #pragma unroll
            for (int n = 0; n < 4; ++n)
                acc[m][n] = __builtin_amdgcn_mfma_f32_16x16x32_bf16(a[m], b[n], acc[m][n], 0, 0, 0);
    };

    const int kSteps = TRI ? (rt + 1) * 4 : 16;    // always even

    stage(lds[0], 0);
    stage(lds[1], 64);

    #pragma unroll 1
    for (int ks = 0; ks < kSteps; ks += 2) {
        const bool more = (ks + 2 < kSteps);
        // ---- phase A: tile ks in lds[0] ----
        asm volatile("s_waitcnt vmcnt(4)" ::: "memory");   // tile ks landed
        __builtin_amdgcn_s_barrier(); CFENCE;
        compute(lds[0]);
        CFENCE; __builtin_amdgcn_s_barrier();
        if (more) stage(lds[0], (ks + 2) * 64);
        // ---- phase B: tile ks+1 in lds[1] ----
        if (more) asm volatile("s_waitcnt vmcnt(4)" ::: "memory");
        else      asm volatile("s_waitcnt vmcnt(0)" ::: "memory");
        __builtin_amdgcn_s_barrier(); CFENCE;
        compute(lds[1]);
        CFENCE; __builtin_amdgcn_s_barrier();
        if (more) stage(lds[1], (ks + 3) * 64);
    }

    // ---- epilogue: C/D layout col=lane&15, row=(lane>>4)*4+j ----
    const int cb = ct * 128 + wc * 64 + l15;
    const int rb = rt * 128 + wr * 64 + (kq << 2);
    #pragma unroll
    for (int m = 0; m < 4; ++m) {
        #pragma unroll
        for (int n = 0; n < 4; ++n) {
            const int c = cb + n * 16;
            #pragma unroll
            for (int j = 0; j < 4; ++j) {
                const int r = rb + m * 16 + j;
                float v = acc[m][n][j];
                const size_t idx = zb * sC + (size_t)r * 512 + c;
                if (EPI == 0) {
                    out0[idx] = f2bf(actf(v));
                } else if (EPI == 1) {
                    float tp = actf(v + bias[c]);
                    out0[idx] = f2bf(tp);
                    out1[idx] = f2bf(actf(zrow[r & 511] * tp));
                } else if (EPI == 2) {
                    out0[idx] = f2bf(actf(v + bias[c]));
                } else if (EPI == 3) {
                    out0[idx] = f2bf(fmaxf(v + bias[c], 0.0f));
                } else {
                    outf[idx] = v + bias[c];
                }
            }
        }
    }
}

// comb[b] = bf16( x0[b]/5000 + sum_c tp[b,c] + sum_c tz[b,c] )
__global__ __launch_bounds__(256) void reduce_both(
    const unsigned short* __restrict__ tp,
    const unsigned short* __restrict__ tz,
    const float* __restrict__ x0,
    unsigned short* __restrict__ comb)
{
    size_t idx = (size_t)blockIdx.x * 256 + threadIdx.x;   // float4 slot
    size_t b = idx >> 16;                                  // / (HI/4)
    size_t p = (idx & 65535) * 4;
    float4 xv = *(const float4*)&x0[(b * Cn) * HI + p];
    float s0 = xv.x * SC, s1 = xv.y * SC, s2 = xv.z * SC, s3 = xv.w * SC;
    #pragma unroll
    for (int c = 0; c < Cn; ++c) {
        size_t q = (b * Cn + c) * HI + p;
        ushort4 a = *(const ushort4*)&tp[q];
        ushort4 d = *(const ushort4*)&tz[q];
        s0 += bf2f(a.x) + bf2f(d.x);
        s1 += bf2f(a.y) + bf2f(d.y);
        s2 += bf2f(a.z) + bf2f(d.z);
        s3 += bf2f(a.w) + bf2f(d.w);
    }
    ushort4 o;
    o.x = f2bf(s0); o.y = f2bf(s1); o.z = f2bf(s2); o.w = f2bf(s3);
    *(ushort4*)&comb[b * HI + p] = o;
}

// xst[bc][i][k] = bf16( x[bc][k][i] * act(mask[k][i]) / 5000 )
__global__ __launch_bounds__(256) void transpose_mask(
    const float* __restrict__ x, const float* __restrict__ mask,
    unsigned short* __restrict__ xst)
{
    __shared__ float t[64][65];
    const int bc = blockIdx.z;
    const int i0 = blockIdx.x * 64, k0 = blockIdx.y * 64;
    const int r4 = threadIdx.x >> 6, cc = threadIdx.x & 63;
    const float* xp = x + (size_t)bc * HI;
    #pragma unroll
    for (int it = 0; it < 16; ++it) {
        int kl = it * 4 + r4;
        size_t g = (size_t)(k0 + kl) * In + i0 + cc;
        t[kl][cc] = xp[g] * (actf(mask[g]) * SC);
    }
    __syncthreads();
    unsigned short* op = xst + (size_t)bc * HI;
    #pragma unroll
    for (int it = 0; it < 16; ++it) {
        int il = it * 4 + r4;
        op[(size_t)(i0 + il) * Hn + k0 + cc] = f2bf(t[cc][il]);
    }
}

__global__ __launch_bounds__(256) void prep_wpe_bf(
    const float* __restrict__ Wp, const float* __restrict__ Wpd,
    unsigned short* __restrict__ o)
{
    int idx = blockIdx.x * 256 + threadIdx.x;
    int i = idx >> 9, j = idx & 511;
    o[idx] = f2bf(Wp[idx] + (i == j ? Wpd[i] : 0.0f));
}

__global__ __launch_bounds__(256) void conv_bf(
    const float* __restrict__ s, unsigned short* __restrict__ o)
{
    int idx = blockIdx.x * 256 + threadIdx.x;
    o[idx] = f2bf(s[idx]);
}

__global__ __launch_bounds__(64) void rowsum(
    const float* __restrict__ W, float* __restrict__ zr)
{
    int h = blockIdx.x, l = threadIdx.x;
    float s = 0.0f;
    for (int k = l; k < Hn; k += 64) s += W[h * Hn + k];
    #pragma unroll
    for (int off = 32; off; off >>= 1) s += __shfl_down(s, off, 64);
    if (!l) zr[h] = s;
}

} // namespace

extern "C" void kernel_launch(void* const* d_in, const int* in_sizes, int n_in,
                              void* d_out, int out_size, void* d_ws, size_t ws_size,
                              hipStream_t stream)
{
    const float* input  = (const float*)d_in[0];
    const float* p_mask = (const float*)d_in[1];
    const float* Wp     = (const float*)d_in[2];
    const float* Wpd    = (const float*)d_in[3];
    const float* Wzp    = (const float*)d_in[4];
    const float* plw    = (const float*)d_in[5];
    const float* plb    = (const float*)d_in[6];
    const float* zlw    = (const float*)d_in[7];
    const float* zlb    = (const float*)d_in[8];
    const float* f1w    = (const float*)d_in[9];
    const float* f1b    = (const float*)d_in[10];
    const float* f2w    = (const float*)d_in[11];
    const float* f2b    = (const float*)d_in[12];

    constexpr size_t WB = 512 * 512 * 2;   // one bf16 weight matrix
    char* w = (char*)d_ws;
    auto alloc = [&](size_t bytes) { char* p = w; w += (bytes + 255) & ~255ull; return p; };

    unsigned short* Wpeb  = (unsigned short*)alloc(WB);
    unsigned short* plwb  = (unsigned short*)alloc(WB);
    unsigned short* zlwb  = (unsigned short*)alloc(WB);
    unsigned short* f1wb  = (unsigned short*)alloc(WB);
    unsigned short* f2wb  = (unsigned short*)alloc(WB);
    float*          zrw   = (float*)alloc(512 * 4);
    unsigned short* combb = (unsigned short*)alloc((size_t)Bn * HI * 2);   // 16.8 MB
    unsigned short* out1  = (unsigned short*)alloc((size_t)Bn * HI * 2);   // 16.8 MB

    size_t fixedB = (size_t)(w - (char*)d_ws);
    int chunk = 32;
    while (chunk > 1 &&
           fixedB + 4ull * (size_t)chunk * Cn * HI * 2 + 4096 > ws_size)
        chunk >>= 1;
    const size_t CB = (size_t)chunk * Cn * HI * 2;
    unsigned short* xst   = (unsigned short*)alloc(CB);   // reused for tz
    unsigned short* tpact = (unsigned short*)alloc(CB);
    unsigned short* tpb   = (unsigned short*)alloc(CB);
    unsigned short* tzin  = (unsigned short*)alloc(CB);
    unsigned short* tzb   = xst;

    prep_wpe_bf<<<512 * 512 / 256, 256, 0, stream>>>(Wp, Wpd, Wpeb);
    conv_bf<<<1024, 256, 0, stream>>>(plw, plwb);
    conv_bf<<<1024, 256, 0, stream>>>(zlw, zlwb);
    conv_bf<<<1024, 256, 0, stream>>>(f1w, f1wb);
    conv_bf<<<1024, 256, 0, stream>>>(f2w, f2wb);
    rowsum<<<512, 64, 0, stream>>>(Wzp, zrw);

    for (int b0 = 0; b0 < Bn; b0 += chunk) {
        const int nc = chunk * Cn;
        const float* inp_c = input + (size_t)b0 * Cn * HI;

        // xst = bf16(x^T * act(mask)/5000)
        transpose_mask<<<dim3(8, 8, nc), 256, 0, stream>>>(inp_c, p_mask, xst);
        // G1: tpact[bc] = act(Wpe @ xst[bc]^T)  — PCOL (xst streamed) + TRI
        mfma_gemm<0, true, true><<<nc * 16, 256, 0, stream>>>(
            Wpeb, xst, nullptr, nullptr, tpact, nullptr, nullptr, HI, HI);
        // G2: tp = act(tpact @ plw^T + plb); tzin = act(zrow*tp)
        mfma_gemm<1, false, false><<<nc * 16, 256, 0, stream>>>(
            tpact, plwb, plb, zrw, tpb, tzin, nullptr, 0, 0);
        // G3: tz = act(tzin @ zlw^T + zlb)
        mfma_gemm<2, false, false><<<nc * 16, 256, 0, stream>>>(
            tzin, zlwb, zlb, nullptr, tzb, nullptr, nullptr, 0, 0);
        // comb = x0/5000 + sum_c tp + sum_c tz
        reduce_both<<<chunk * 256, 256, 0, stream>>>(
            tpb, tzb, inp_c, combb + (size_t)b0 * HI);
    }

    // fc1: out1 = relu(combb @ f1w^T + f1b)
    mfma_gemm<3, false, false><<<512, 256, 0, stream>>>(
        combb, f1wb, f1b, nullptr, out1, nullptr, nullptr, 0, 0);
    // fc2: out = out1 @ f2w^T + f2b   (fp32)
    mfma_gemm<4, false, false><<<512, 256, 0, stream>>>(
        out1, f2wb, f2b, nullptr, nullptr, nullptr, (float*)d_out, 0, 0);
}